// Round 4
// baseline (209.956 us; speedup 1.0000x reference)
//
#include <hip/hip_runtime.h>
#include <hip/hip_bf16.h>
#include <stdint.h>

// ---------------------------------------------------------------------------
// TensorNet: fused encoder MLP (128->256->256->256, relu) over 32x4096 tokens,
// per-batch mean -> p = relu(m^2) -> decoder MLP (256->512->512->10).
// Inputs/outputs fp32. Encoder via bf16 MFMA + fp32 accum.
// R3: encoder was 76us, MfmaUtil 23%, 2.88M LDS bank conflicts — epilogue did
// 64 scalar f2b + 64 ds_write_b16 per thread (C-layout column-runs vs
// row-major h). R4: swap MFMA operand roles (A=weights, M=hidden; B=act,
// N=tokens) so C/D row-runs (q*4+r) align with contiguous hidden dim:
// epilogue = float4 bias + 2x v_cvt_pk_bf16_f32 + 1x ds_write_b64 per tile.
// ---------------------------------------------------------------------------

#define NIN   128
#define NHID  256
#define NDEC  512
#define NOUTC 10
#define BATCH 32
#define NTOK  4096
#define MTILE 64
#define TPB   64               // encoder blocks per batch (4096/64)
#define NBLK  (BATCH * TPB)    // 2048 encoder blocks
#define XPAD  136              // x-tile LDS row stride (bf16 elems)
#define HPAD  264              // h-tile LDS row stride (bf16 elems), 528B rows

typedef short bf16x8 __attribute__((ext_vector_type(8)));
typedef float floatx4 __attribute__((ext_vector_type(4)));

__device__ __forceinline__ uint16_t f2b(float f) {
  union { float f; uint32_t u; } v; v.f = f;
  uint32_t r = v.u + 0x7FFFu + ((v.u >> 16) & 1u);   // RNE
  return (uint16_t)(r >> 16);
}
__device__ __forceinline__ uint32_t pkbf(float lo, float hi) {
  __hip_bfloat162 h = __float22bfloat162_rn(float2{lo, hi});  // v_cvt_pk_bf16_f32
  union { __hip_bfloat162 h; uint32_t u; } c; c.h = h;
  return c.u;
}

// ---------------------------------------------------------------------------
// Pack W1/W2/W3 (fp32 [K][256] row-major) into bf16 MFMA-fragment order:
//   packed[((mt*KC + kc)*64 + lane)*8 + j] =
//       bf16( W[kc*32 + (lane>>4)*8 + j][mt*16 + (lane&15)] )
// Serves as the encoder's A-operand (A[m][k] = W[k][m], m=hidden out).
// Also zero-inits the msum accumulator (poisoned 0xAA by the harness).
// ---------------------------------------------------------------------------
__global__ __launch_bounds__(256) void pack_weights(
    const float* __restrict__ W1, const float* __restrict__ W2,
    const float* __restrict__ W3, uint16_t* __restrict__ out,
    float* __restrict__ msum) {
  int p = blockIdx.x * blockDim.x + threadIdx.x;
  if (p < BATCH * NHID) msum[p] = 0.f;
  const float* W; int K; int base;
  if (p < 32768)      { W = W1; K = NIN;  base = 0; }
  else if (p < 98304) { W = W2; K = NHID; base = 32768; p -= 32768; }
  else                { W = W3; K = NHID; base = 98304; p -= 98304; }
  int j    = p & 7;
  int lane = (p >> 3) & 63;
  int rest = p >> 9;
  int KC = K >> 5;               // K/32 k-chunks
  int kc = rest % KC;
  int mt = rest / KC;
  int m = mt * 16 + (lane & 15);
  int k = kc * 32 + ((lane >> 4) << 3) + j;
  out[base + (((mt * KC + kc) * 64 + lane) << 3) + j] = f2b(W[k * NHID + m]);
}

// ---------------------------------------------------------------------------
// Fused encoder. Block = 256 thr (4 waves), 64 tokens. Wave w owns hidden
// rows [64w, 64w+64) (A-operand = packed weights); all 4 token-tiles shared
// (B-operand from LDS). D tile: lane holds j = 64w+jt*16+q*4+r (contiguous
// r-run) at token t = tt*16+l15 -> b64 epilogue writes.
// Layer3 fused: bias+relu+token-sum via LDS scratch -> atomicAdd msum.
// ---------------------------------------------------------------------------
__global__ __launch_bounds__(256) void encoder(
    const float* __restrict__ x,        // [BATCH*NTOK][NIN] fp32
    const uint16_t* __restrict__ pW,    // packed bf16 weights
    const float* __restrict__ b1,
    const float* __restrict__ b2,
    const float* __restrict__ b3,
    float* __restrict__ msum) {         // [BATCH][NHID] fp32 accum
  __shared__ uint16_t Hs[MTILE * HPAD]; // 33792 B; x-tile & scratch alias

  const int tid  = threadIdx.x;
  const int wave = tid >> 6;
  const int lane = tid & 63;
  const int l15  = lane & 15;
  const int q    = lane >> 4;
  const int tok0 = blockIdx.x * MTILE;

  const uint16_t* pW1 = pW;             // KC=4
  const uint16_t* pW2 = pW + 32768;     // KC=8
  const uint16_t* pW3 = pW + 98304;     // KC=8

  // ---- stage x tile: fp32 -> bf16 (packed cvt), rows stride XPAD ----
  {
    const int row = tid >> 2;
    const int c0  = (tid & 3) * 32;
    const float* xr = x + (size_t)(tok0 + row) * NIN + c0;
    for (int i = 0; i < 8; ++i) {
      float4 v = *(const float4*)(xr + i * 4);
      uint2 u = make_uint2(pkbf(v.x, v.y), pkbf(v.z, v.w));
      *(uint2*)&Hs[row * XPAD + c0 + i * 4] = u;
    }
  }
  __syncthreads();

  floatx4 acc[4][4];   // [jt][tt]

  // ---------------- layer 1: K = 128, A = W1^T, B = x ----------------
  for (int jt = 0; jt < 4; ++jt)
    for (int tt = 0; tt < 4; ++tt)
      acc[jt][tt] = (floatx4){0.f, 0.f, 0.f, 0.f};
  for (int kc = 0; kc < 4; ++kc) {
    bf16x8 a[4], b[4];
    for (int jt = 0; jt < 4; ++jt)
      a[jt] = *(const bf16x8*)(pW1 + ((((wave * 4 + jt) * 4 + kc) * 64 + lane) << 3));
    for (int tt = 0; tt < 4; ++tt)
      b[tt] = *(const bf16x8*)&Hs[(tt * 16 + l15) * XPAD + kc * 32 + q * 8];
    for (int jt = 0; jt < 4; ++jt)
      for (int tt = 0; tt < 4; ++tt)
        acc[jt][tt] = __builtin_amdgcn_mfma_f32_16x16x32_bf16(
            a[jt], b[tt], acc[jt][tt], 0, 0, 0);
  }
  __syncthreads();   // all x-tile reads done before h1 overwrites the region

  // bias + relu -> Hs (h1), rows = tokens, stride HPAD
  for (int jt = 0; jt < 4; ++jt) {
    const int jbase = wave * 64 + jt * 16 + q * 4;
    const float4 bb = *(const float4*)&b1[jbase];
    for (int tt = 0; tt < 4; ++tt) {
      const int t = tt * 16 + l15;
      float v0 = fmaxf(acc[jt][tt][0] + bb.x, 0.f);
      float v1 = fmaxf(acc[jt][tt][1] + bb.y, 0.f);
      float v2 = fmaxf(acc[jt][tt][2] + bb.z, 0.f);
      float v3 = fmaxf(acc[jt][tt][3] + bb.w, 0.f);
      *(uint2*)&Hs[t * HPAD + jbase] = make_uint2(pkbf(v0, v1), pkbf(v2, v3));
    }
  }
  __syncthreads();

  // ---------------- layer 2: K = 256, A = W2^T, B = h1 ----------------
  for (int jt = 0; jt < 4; ++jt)
    for (int tt = 0; tt < 4; ++tt)
      acc[jt][tt] = (floatx4){0.f, 0.f, 0.f, 0.f};
  for (int kc = 0; kc < 8; ++kc) {
    bf16x8 a[4], b[4];
    for (int jt = 0; jt < 4; ++jt)
      a[jt] = *(const bf16x8*)(pW2 + ((((wave * 4 + jt) * 8 + kc) * 64 + lane) << 3));
    for (int tt = 0; tt < 4; ++tt)
      b[tt] = *(const bf16x8*)&Hs[(tt * 16 + l15) * HPAD + kc * 32 + q * 8];
    for (int jt = 0; jt < 4; ++jt)
      for (int tt = 0; tt < 4; ++tt)
        acc[jt][tt] = __builtin_amdgcn_mfma_f32_16x16x32_bf16(
            a[jt], b[tt], acc[jt][tt], 0, 0, 0);
  }
  __syncthreads();   // everyone done READING h1 before overwrite
  for (int jt = 0; jt < 4; ++jt) {
    const int jbase = wave * 64 + jt * 16 + q * 4;
    const float4 bb = *(const float4*)&b2[jbase];
    for (int tt = 0; tt < 4; ++tt) {
      const int t = tt * 16 + l15;
      float v0 = fmaxf(acc[jt][tt][0] + bb.x, 0.f);
      float v1 = fmaxf(acc[jt][tt][1] + bb.y, 0.f);
      float v2 = fmaxf(acc[jt][tt][2] + bb.z, 0.f);
      float v3 = fmaxf(acc[jt][tt][3] + bb.w, 0.f);
      *(uint2*)&Hs[t * HPAD + jbase] = make_uint2(pkbf(v0, v1), pkbf(v2, v3));
    }
  }
  __syncthreads();

  // ---------------- layer 3: K = 256, A = W3^T, B = h2, fused mean ---------
  for (int jt = 0; jt < 4; ++jt)
    for (int tt = 0; tt < 4; ++tt)
      acc[jt][tt] = (floatx4){0.f, 0.f, 0.f, 0.f};
  for (int kc = 0; kc < 8; ++kc) {
    bf16x8 a[4], b[4];
    for (int jt = 0; jt < 4; ++jt)
      a[jt] = *(const bf16x8*)(pW3 + ((((wave * 4 + jt) * 8 + kc) * 64 + lane) << 3));
    for (int tt = 0; tt < 4; ++tt)
      b[tt] = *(const bf16x8*)&Hs[(tt * 16 + l15) * HPAD + kc * 32 + q * 8];
    for (int jt = 0; jt < 4; ++jt)
      for (int tt = 0; tt < 4; ++tt)
        acc[jt][tt] = __builtin_amdgcn_mfma_f32_16x16x32_bf16(
            a[jt], b[tt], acc[jt][tt], 0, 0, 0);
  }
  __syncthreads();   // all h2 reads done before scratch overwrites Hs

  // bias + relu + partial token-sum (over this lane's 4 t-tiles at l15)
  // scratch[(wave*4+jt)*4+q][l15] = float4(s0..s3); then 256 thr <-> 256 j's
  {
    float4* scratch = (float4*)Hs;      // 64*16 float4 = 16 KB
    for (int jt = 0; jt < 4; ++jt) {
      const int jbase = wave * 64 + jt * 16 + q * 4;
      const float4 bb = *(const float4*)&b3[jbase];
      float s0 = 0.f, s1 = 0.f, s2 = 0.f, s3 = 0.f;
      for (int tt = 0; tt < 4; ++tt) {
        s0 += fmaxf(acc[jt][tt][0] + bb.x, 0.f);
        s1 += fmaxf(acc[jt][tt][1] + bb.y, 0.f);
        s2 += fmaxf(acc[jt][tt][2] + bb.z, 0.f);
        s3 += fmaxf(acc[jt][tt][3] + bb.w, 0.f);
      }
      scratch[((wave * 4 + jt) * 4 + q) * 16 + l15] =
          (float4){s0, s1, s2, s3};
    }
  }
  __syncthreads();
  {
    const int c = tid >> 2;             // (wave*4+jt)*4+q
    const int r = tid & 3;
    const float* sf = (const float*)Hs;
    float v = 0.f;
    for (int l = 0; l < 16; ++l)
      v += sf[c * 64 + l * 4 + r];
    const int wv = c >> 4, jt = (c >> 2) & 3, qq = c & 3;
    const int j = wv * 64 + jt * 16 + qq * 4 + r;
    const int batch = blockIdx.x >> 6;  // / TPB
    atomicAdd(&msum[batch * NHID + j], v);
  }
}

// ---------------------------------------------------------------------------
// Decoder, split for parallelism (R2: monolithic = 32 blocks, 75us).
// ---------------------------------------------------------------------------
__global__ __launch_bounds__(256) void dec1_kernel(
    const float* __restrict__ msum, const float* __restrict__ D1,
    const float* __restrict__ c1, float* __restrict__ d1out) {
  __shared__ float p[NHID];
  __shared__ float red[256];
  const int b = blockIdx.y, jc = blockIdx.x, t = threadIdx.x;
  {
    float m = msum[b * NHID + t] * (1.f / NTOK);
    p[t] = m * m;                       // relu(m^2) == m^2
  }
  __syncthreads();
  const int j  = jc * 64 + (t & 63);
  const int kc = t >> 6;                // 0..3, 64 k's each
  float s = 0.f;
  for (int k = kc * 64; k < kc * 64 + 64; ++k)
    s += p[k] * D1[k * NDEC + j];
  red[t] = s;
  __syncthreads();
  if (t < 64) {
    float v = red[t] + red[64 + t] + red[128 + t] + red[192 + t]
            + c1[jc * 64 + t];
    d1out[b * NDEC + jc * 64 + t] = fmaxf(v, 0.f);
  }
}

__global__ __launch_bounds__(256) void dec2_kernel(
    const float* __restrict__ d1, const float* __restrict__ D2,
    const float* __restrict__ c2, float* __restrict__ d2out) {
  __shared__ float h[NDEC];
  __shared__ float red[256];
  const int b = blockIdx.y, jc = blockIdx.x, t = threadIdx.x;
  h[t]       = d1[b * NDEC + t];
  h[t + 256] = d1[b * NDEC + t + 256];
  __syncthreads();
  const int j  = jc * 64 + (t & 63);
  const int kc = t >> 6;                // 0..3, 128 k's each
  float s = 0.f;
  for (int k = kc * 128; k < kc * 128 + 128; ++k)
    s += h[k] * D2[k * NDEC + j];
  red[t] = s;
  __syncthreads();
  if (t < 64) {
    float v = red[t] + red[64 + t] + red[128 + t] + red[192 + t]
            + c2[jc * 64 + t];
    d2out[b * NDEC + jc * 64 + t] = fmaxf(v, 0.f);
  }
}

__global__ __launch_bounds__(256) void dec3_kernel(
    const float* __restrict__ d2, const float* __restrict__ D3,
    const float* __restrict__ c3, float* __restrict__ out) {
  __shared__ float h[NDEC];
  __shared__ float red[256];
  const int b = blockIdx.x, t = threadIdx.x;
  h[t]       = d2[b * NDEC + t];
  h[t + 256] = d2[b * NDEC + t + 256];
  __syncthreads();
  const int j  = t & 15;                // 16 slots, NOUTC=10 valid
  const int kc = t >> 4;                // 16 chunks x 32 k's
  float s = 0.f;
  if (j < NOUTC)
    for (int k = kc * 32; k < kc * 32 + 32; ++k)
      s += h[k] * D3[k * NOUTC + j];
  red[t] = s;
  __syncthreads();
  if (t < NOUTC) {
    float v = c3[t];
    for (int i = 0; i < 16; ++i) v += red[i * 16 + t];
    out[b * NOUTC + t] = v;
  }
}

// ---------------------------------------------------------------------------
extern "C" void kernel_launch(void* const* d_in, const int* in_sizes, int n_in,
                              void* d_out, int out_size, void* d_ws, size_t ws_size,
                              hipStream_t stream) {
  const float* x  = (const float*)d_in[0];
  const float* W1 = (const float*)d_in[1];
  const float* b1 = (const float*)d_in[2];
  const float* W2 = (const float*)d_in[3];
  const float* b2 = (const float*)d_in[4];
  const float* W3 = (const float*)d_in[5];
  const float* b3 = (const float*)d_in[6];
  const float* D1 = (const float*)d_in[7];
  const float* c1 = (const float*)d_in[8];
  const float* D2 = (const float*)d_in[9];
  const float* c2 = (const float*)d_in[10];
  const float* D3 = (const float*)d_in[11];
  const float* c3 = (const float*)d_in[12];

  // ws layout: [0,320K) packed bf16 W | [384K,416K) msum | [448K,512K) d1 |
  //            [512K,576K) d2
  uint16_t* pW   = (uint16_t*)d_ws;
  float*    msum = (float*)((char*)d_ws + 384 * 1024);
  float*    d1s  = (float*)((char*)d_ws + 448 * 1024);
  float*    d2s  = (float*)((char*)d_ws + 512 * 1024);

  pack_weights<<<640, 256, 0, stream>>>(W1, W2, W3, pW, msum);
  encoder<<<NBLK, 256, 0, stream>>>(x, pW, b1, b2, b3, msum);
  dec1_kernel<<<dim3(8, BATCH), 256, 0, stream>>>(msum, D1, c1, d1s);
  dec2_kernel<<<dim3(8, BATCH), 256, 0, stream>>>(d1s, D2, c2, d2s);
  dec3_kernel<<<BATCH, 256, 0, stream>>>(d2s, D3, c3, (float*)d_out);
}